// Round 3
// baseline (606.208 us; speedup 1.0000x reference)
//
#include <hip/hip_runtime.h>

// Problem constants
#define M_TOT 8192      // 4 * 2048
#define K_TOT 4096      // IN_FEATURES
#define N_TOT 4096      // OUT_FEATURES
#define RANK  64
#define SCALING 0.25f

typedef __bf16 bf16x8 __attribute__((ext_vector_type(8)));
typedef float floatx4 __attribute__((ext_vector_type(4)));

static __device__ __forceinline__ unsigned short f32_to_bf16(float f) {
  unsigned int u = __float_as_uint(f);
  u += 0x7FFFu + ((u >> 16) & 1u);   // round-to-nearest-even
  return (unsigned short)(u >> 16);
}

// async global->LDS, 16B per lane. LDS dest must be base + lane*16 contiguous.
static __device__ __forceinline__ void async_ld16(const void* g, void* l) {
  __builtin_amdgcn_global_load_lds(
      (const __attribute__((address_space(1))) unsigned int*)g,
      (__attribute__((address_space(3))) unsigned int*)l, 16, 0, 0);
}

// ---------------- kernel 1: convert x fp32 -> bf16 ----------------
__global__ __launch_bounds__(256) void cvt_x_kernel(const float4* __restrict__ x,
                                                    ushort4* __restrict__ xb) {
  int i = blockIdx.x * 256 + threadIdx.x;   // grid sized exactly: no bounds check
  float4 v = x[i];
  ushort4 o;
  o.x = f32_to_bf16(v.x);
  o.y = f32_to_bf16(v.y);
  o.z = f32_to_bf16(v.z);
  o.w = f32_to_bf16(v.w);
  xb[i] = o;
}

// ---------------- kernel 2: prep — dequant W + convert A,B to bf16 ----------
// blocks [0,16384):      Weff = bf16(wq*scale), int4 load / ushort4 store
// blocks [16384,16640):  Ab = bf16(A)            (64*4096 elems)
// blocks [16640,16896):  Bb = bf16(0.25*B)       (4096*64 elems; SCALING folded)
__global__ __launch_bounds__(256) void prep_kernel(
    const int* __restrict__ wq, const float* __restrict__ scale_p,
    const float* __restrict__ A, const float* __restrict__ B,
    unsigned short* __restrict__ Weff, unsigned short* __restrict__ Ab,
    unsigned short* __restrict__ Bb) {
  const int blk = blockIdx.x;
  const int tid = threadIdx.x;
  if (blk < 16384) {
    const float scale = scale_p[0];
    const size_t i = (size_t)(blk * 256 + tid) * 4;
    const int4 wv = *(const int4*)(wq + i);
    ushort4 st;
    st.x = f32_to_bf16((float)wv.x * scale);
    st.y = f32_to_bf16((float)wv.y * scale);
    st.z = f32_to_bf16((float)wv.z * scale);
    st.w = f32_to_bf16((float)wv.w * scale);
    *(ushort4*)(Weff + i) = st;
  } else if (blk < 16640) {
    const size_t i = (size_t)((blk - 16384) * 256 + tid) * 4;
    const float4 v = *(const float4*)(A + i);
    ushort4 st;
    st.x = f32_to_bf16(v.x);
    st.y = f32_to_bf16(v.y);
    st.z = f32_to_bf16(v.z);
    st.w = f32_to_bf16(v.w);
    *(ushort4*)(Ab + i) = st;
  } else {
    const size_t i = (size_t)((blk - 16640) * 256 + tid) * 4;
    const float4 v = *(const float4*)(B + i);
    ushort4 st;
    st.x = f32_to_bf16(v.x * SCALING);
    st.y = f32_to_bf16(v.y * SCALING);
    st.z = f32_to_bf16(v.z * SCALING);
    st.w = f32_to_bf16(v.w * SCALING);
    *(ushort4*)(Bb + i) = st;
  }
}

// ---------------- kernel 3: y = bf16(x @ A^T)  [M_TOT][RANK] ----------------
// M-tile 64 (4 waves x 16 rows), N = RANK = 64 (4 col-tiles/wave), BK=64 as
// two [64][32] LDS sub-tiles, global_load_lds staging. Grid = 128 blocks.
__global__ __launch_bounds__(256) void lora_y_kernel(
    const unsigned short* __restrict__ Xb,   // [M_TOT][K_TOT]
    const unsigned short* __restrict__ Ab,   // [RANK][K_TOT]
    unsigned short* __restrict__ Yb) {       // [M_TOT][RANK]
  __shared__ __align__(16) unsigned short Xs[2 * 64 * 32];  // 8 KB
  __shared__ __align__(16) unsigned short As[2 * 64 * 32];  // 8 KB

  const int tid = threadIdx.x;
  const int lane = tid & 63;
  const int wave = tid >> 6;
  const int m0 = blockIdx.x * 64;

  const int sRow = tid >> 2;        // 0..63
  const int sCol = (tid & 3) * 8;   // 0,8,16,24
  const unsigned short* xg = Xb + (size_t)(m0 + sRow) * K_TOT + sCol;
  const unsigned short* ag = Ab + (size_t)sRow * K_TOT + sCol;
  unsigned short* lx0 = Xs + tid * 8;
  unsigned short* lx1 = Xs + 64 * 32 + tid * 8;
  unsigned short* la0 = As + tid * 8;
  unsigned short* la1 = As + 64 * 32 + tid * 8;

  const unsigned short* px = Xs + (wave * 16 + (lane & 15)) * 32 + (lane >> 4) * 8;
  const unsigned short* pav = As + (lane & 15) * 32 + (lane >> 4) * 8;

  floatx4 acc[4] = {};
  for (int kt = 0; kt < K_TOT; kt += 64) {
    __syncthreads();
    async_ld16(xg + kt, lx0);
    async_ld16(xg + kt + 32, lx1);
    async_ld16(ag + kt, la0);
    async_ld16(ag + kt + 32, la1);
    __syncthreads();
#pragma unroll
    for (int ks = 0; ks < 2; ++ks) {
      bf16x8 xf = *(const bf16x8*)(px + ks * 64 * 32);
#pragma unroll
      for (int j = 0; j < 4; ++j) {
        bf16x8 af = *(const bf16x8*)(pav + ks * 64 * 32 + j * 16 * 32);
        acc[j] = __builtin_amdgcn_mfma_f32_16x16x32_bf16(xf, af, acc[j], 0, 0, 0);
      }
    }
  }
  const int row0 = m0 + wave * 16 + ((lane >> 4) << 2);
  const int col0 = lane & 15;
#pragma unroll
  for (int j = 0; j < 4; ++j)
#pragma unroll
    for (int r = 0; r < 4; ++r)
      Yb[(size_t)(row0 + r) * RANK + (col0 + j * 16)] = f32_to_bf16(acc[j][r]);
}

// ---------------- kernel 4: main GEMM, out = [Xb|Yb] @ [Weff|Bb]^T ----------
// m97 structure, BK=64 as two [128][32] sub-tiles, 64 K-iters over Xb/Weff
// plus ONE peeled iteration staging Yb (A-side) and Bb (B-side) = LoRA term.
__global__ __launch_bounds__(256) void gemm_kernel(
    const unsigned short* __restrict__ Xb,   // [M_TOT][K_TOT]
    const unsigned short* __restrict__ Wb,   // [N_TOT][K_TOT]
    const unsigned short* __restrict__ Yb,   // [M_TOT][RANK]
    const unsigned short* __restrict__ Bb,   // [N_TOT][RANK] (0.25 folded)
    float* __restrict__ out) {               // [M_TOT][N_TOT]
  __shared__ __align__(16) unsigned short As[2 * 128 * 32];  // 16 KB
  __shared__ __align__(16) unsigned short Bs[2 * 128 * 32];  // 16 KB

  const int tid = threadIdx.x;
  const int lane = tid & 63;
  const int wave = tid >> 6;
  const int wm = wave >> 1;
  const int wn = wave & 1;

  const int bM = blockIdx.y * 128;
  const int bN = blockIdx.x * 128;

  const int sRow = tid >> 2;        // 0..63
  const int sCol = (tid & 3) * 8;   // 0,8,16,24
  const unsigned short* xg0 = Xb + (size_t)(bM + sRow) * K_TOT + sCol;
  const unsigned short* xg1 = xg0 + (size_t)64 * K_TOT;
  const unsigned short* wg0 = Wb + (size_t)(bN + sRow) * K_TOT + sCol;
  const unsigned short* wg1 = wg0 + (size_t)64 * K_TOT;
  unsigned short* la00 = As + tid * 8;
  unsigned short* la01 = As + 64 * 32 + tid * 8;
  unsigned short* la10 = As + 128 * 32 + tid * 8;
  unsigned short* la11 = As + 128 * 32 + 64 * 32 + tid * 8;
  unsigned short* lb00 = Bs + tid * 8;
  unsigned short* lb01 = Bs + 64 * 32 + tid * 8;
  unsigned short* lb10 = Bs + 128 * 32 + tid * 8;
  unsigned short* lb11 = Bs + 128 * 32 + 64 * 32 + tid * 8;

  const unsigned short* pa = As + ((wm * 64) + (lane & 15)) * 32 + (lane >> 4) * 8;
  const unsigned short* pb = Bs + ((wn * 64) + (lane & 15)) * 32 + (lane >> 4) * 8;

  floatx4 acc[4][4] = {};

  for (int kt = 0; kt < K_TOT; kt += 64) {
    __syncthreads();
    async_ld16(xg0 + kt, la00);
    async_ld16(xg1 + kt, la01);
    async_ld16(xg0 + kt + 32, la10);
    async_ld16(xg1 + kt + 32, la11);
    async_ld16(wg0 + kt, lb00);
    async_ld16(wg1 + kt, lb01);
    async_ld16(wg0 + kt + 32, lb10);
    async_ld16(wg1 + kt + 32, lb11);
    __syncthreads();

#pragma unroll
    for (int ks = 0; ks < 2; ++ks) {
      const unsigned short* pak = pa + ks * 128 * 32;
      const unsigned short* pbk = pb + ks * 128 * 32;
      bf16x8 af[4], bf[4];
#pragma unroll
      for (int i = 0; i < 4; ++i) af[i] = *(const bf16x8*)(pak + i * 16 * 32);
#pragma unroll
      for (int j = 0; j < 4; ++j) bf[j] = *(const bf16x8*)(pbk + j * 16 * 32);
#pragma unroll
      for (int i = 0; i < 4; ++i)
#pragma unroll
        for (int j = 0; j < 4; ++j)
          acc[i][j] = __builtin_amdgcn_mfma_f32_16x16x32_bf16(af[i], bf[j], acc[i][j], 0, 0, 0);
    }
  }

  // peeled LoRA iteration: A-side = Yb [M][64], B-side = Bb [N][64]
  {
    const unsigned short* yg0 = Yb + (size_t)(bM + sRow) * RANK + sCol;
    const unsigned short* yg1 = yg0 + (size_t)64 * RANK;
    const unsigned short* bg0 = Bb + (size_t)(bN + sRow) * RANK + sCol;
    const unsigned short* bg1 = bg0 + (size_t)64 * RANK;
    __syncthreads();
    async_ld16(yg0, la00);
    async_ld16(yg1, la01);
    async_ld16(yg0 + 32, la10);
    async_ld16(yg1 + 32, la11);
    async_ld16(bg0, lb00);
    async_ld16(bg1, lb01);
    async_ld16(bg0 + 32, lb10);
    async_ld16(bg1 + 32, lb11);
    __syncthreads();
#pragma unroll
    for (int ks = 0; ks < 2; ++ks) {
      const unsigned short* pak = pa + ks * 128 * 32;
      const unsigned short* pbk = pb + ks * 128 * 32;
      bf16x8 af[4], bf[4];
#pragma unroll
      for (int i = 0; i < 4; ++i) af[i] = *(const bf16x8*)(pak + i * 16 * 32);
#pragma unroll
      for (int j = 0; j < 4; ++j) bf[j] = *(const bf16x8*)(pbk + j * 16 * 32);
#pragma unroll
      for (int i = 0; i < 4; ++i)
#pragma unroll
        for (int j = 0; j < 4; ++j)
          acc[i][j] = __builtin_amdgcn_mfma_f32_16x16x32_bf16(af[i], bf[j], acc[i][j], 0, 0, 0);
    }
  }

  const int row0 = bM + wm * 64 + ((lane >> 4) << 2);
  const int col0 = bN + wn * 64 + (lane & 15);
#pragma unroll
  for (int i = 0; i < 4; ++i)
#pragma unroll
    for (int j = 0; j < 4; ++j)
#pragma unroll
      for (int r = 0; r < 4; ++r)
        out[(size_t)(row0 + i * 16 + r) * N_TOT + (col0 + j * 16)] = acc[i][j][r];
}

extern "C" void kernel_launch(void* const* d_in, const int* in_sizes, int n_in,
                              void* d_out, int out_size, void* d_ws, size_t ws_size,
                              hipStream_t stream) {
  const float* x      = (const float*)d_in[0];   // [4,2048,4096] fp32
  const int*   wq     = (const int*)d_in[1];     // [4096,4096] int
  const float* wscale = (const float*)d_in[2];   // [1] fp32
  const float* lora_A = (const float*)d_in[3];   // [64,4096] fp32
  const float* lora_B = (const float*)d_in[4];   // [4096,64] fp32
  float* out = (float*)d_out;

  // workspace layout (bytes):
  // xb   @ 0          : 8192*4096*2 = 67108864
  // weff @ 67108864   : 4096*4096*2 = 33554432
  // yb   @ 100663296  : 8192*64*2   = 1048576
  // ab   @ 101711872  : 64*4096*2   = 524288
  // bb   @ 102236160  : 4096*64*2   = 524288   (total 102760448)
  char* ws = (char*)d_ws;
  unsigned short* xb   = (unsigned short*)(ws);
  unsigned short* weff = (unsigned short*)(ws + 67108864);
  unsigned short* yb   = (unsigned short*)(ws + 100663296);
  unsigned short* ab   = (unsigned short*)(ws + 101711872);
  unsigned short* bb   = (unsigned short*)(ws + 102236160);

  cvt_x_kernel<<<32768, 256, 0, stream>>>((const float4*)x, (ushort4*)xb);
  prep_kernel<<<16896, 256, 0, stream>>>(wq, wscale, lora_A, lora_B, weff, ab, bb);
  lora_y_kernel<<<128, 256, 0, stream>>>(xb, ab, yb);
  gemm_kernel<<<dim3(N_TOT / 128, M_TOT / 128), 256, 0, stream>>>(xb, weff, yb, bb, out);
}

// Round 4
// 596.358 us; speedup vs baseline: 1.0165x; 1.0165x over previous
//
#include <hip/hip_runtime.h>

// Problem constants
#define M_TOT 8192      // 4 * 2048
#define K_TOT 4096      // IN_FEATURES
#define N_TOT 4096      // OUT_FEATURES
#define RANK  64
#define SCALING 0.25f

typedef __bf16 bf16x8 __attribute__((ext_vector_type(8)));
typedef float floatx4 __attribute__((ext_vector_type(4)));
typedef unsigned short ushort8 __attribute__((ext_vector_type(8)));

static __device__ __forceinline__ unsigned short f32_to_bf16(float f) {
  unsigned int u = __float_as_uint(f);
  u += 0x7FFFu + ((u >> 16) & 1u);   // round-to-nearest-even
  return (unsigned short)(u >> 16);
}

// async global->LDS, 16B per lane. LDS dest must be base + lane*16 contiguous.
static __device__ __forceinline__ void async_ld16(const void* g, void* l) {
  __builtin_amdgcn_global_load_lds(
      (const __attribute__((address_space(1))) unsigned int*)g,
      (__attribute__((address_space(3))) unsigned int*)l, 16, 0, 0);
}

// ---------------- kernel 1: prep — dequant W + convert A,B to bf16 ----------
// blocks [0,16384):      Weff = bf16(wq*scale)
// blocks [16384,16640):  Ab = bf16(A)
// blocks [16640,16896):  Bb = bf16(0.25*B)
__global__ __launch_bounds__(256) void prep_kernel(
    const int* __restrict__ wq, const float* __restrict__ scale_p,
    const float* __restrict__ A, const float* __restrict__ B,
    unsigned short* __restrict__ Weff, unsigned short* __restrict__ Ab,
    unsigned short* __restrict__ Bb) {
  const int blk = blockIdx.x;
  const int tid = threadIdx.x;
  if (blk < 16384) {
    const float scale = scale_p[0];
    const size_t i = (size_t)(blk * 256 + tid) * 4;
    const int4 wv = *(const int4*)(wq + i);
    ushort4 st;
    st.x = f32_to_bf16((float)wv.x * scale);
    st.y = f32_to_bf16((float)wv.y * scale);
    st.z = f32_to_bf16((float)wv.z * scale);
    st.w = f32_to_bf16((float)wv.w * scale);
    *(ushort4*)(Weff + i) = st;
  } else if (blk < 16640) {
    const size_t i = (size_t)((blk - 16384) * 256 + tid) * 4;
    const float4 v = *(const float4*)(A + i);
    ushort4 st;
    st.x = f32_to_bf16(v.x);
    st.y = f32_to_bf16(v.y);
    st.z = f32_to_bf16(v.z);
    st.w = f32_to_bf16(v.w);
    *(ushort4*)(Ab + i) = st;
  } else {
    const size_t i = (size_t)((blk - 16640) * 256 + tid) * 4;
    const float4 v = *(const float4*)(B + i);
    ushort4 st;
    st.x = f32_to_bf16(v.x * SCALING);
    st.y = f32_to_bf16(v.y * SCALING);
    st.z = f32_to_bf16(v.z * SCALING);
    st.w = f32_to_bf16(v.w * SCALING);
    *(ushort4*)(Bb + i) = st;
  }
}

// ---------------- kernel 2: fused x->bf16 convert + y = bf16(x @ A^T) -------
// 256 blocks, M-tile 32. Reads x fp32 ONCE: converts in-register, writes xb
// global AND stages into LDS for the rank-64 MFMA. A staged via async_ld16.
// Wave layout: wm = wave&1 (row half), wn = wave>>1 (col half), acc[2].
__global__ __launch_bounds__(256) void cvt_lora_kernel(
    const float* __restrict__ x,             // [M_TOT][K_TOT] fp32
    const unsigned short* __restrict__ Ab,   // [RANK][K_TOT] bf16
    unsigned short* __restrict__ Xb,         // [M_TOT][K_TOT] bf16 out
    unsigned short* __restrict__ Yb) {       // [M_TOT][RANK] bf16 out
  __shared__ __align__(16) unsigned short Xs[2 * 32 * 32];  // 4 KB
  __shared__ __align__(16) unsigned short As[2 * 64 * 32];  // 8 KB

  const int tid = threadIdx.x;
  const int lane = tid & 63;
  const int wave = tid >> 6;
  const int wm = wave & 1;
  const int wn = wave >> 1;
  const int m0 = blockIdx.x * 32;

  // x slice owned by this thread: row xr, 8 cols starting at xc8
  const int xr = tid >> 3;          // 0..31
  const int xc8 = (tid & 7) * 8;    // 0..56
  const int xks = (tid & 7) >> 2;   // k sub-tile 0/1
  const int xcin = xc8 & 31;
  const float* xg = x + (size_t)(m0 + xr) * K_TOT + xc8;
  unsigned short* xbg = Xb + (size_t)(m0 + xr) * K_TOT + xc8;
  unsigned short* lx = Xs + xks * 1024 + xr * 32 + xcin;

  // A staging: sRow 0..63 (rank), sCol 8-wide
  const int sRow = tid >> 2;
  const int sCol = (tid & 3) * 8;
  const unsigned short* ag = Ab + (size_t)sRow * K_TOT + sCol;
  unsigned short* la0 = As + tid * 8;
  unsigned short* la1 = As + 2048 + tid * 8;

  // MFMA fragment pointers
  const unsigned short* px = Xs + (wm * 16 + (lane & 15)) * 32 + (lane >> 4) * 8;
  const unsigned short* pav = As + (wn * 32 + (lane & 15)) * 32 + (lane >> 4) * 8;

  floatx4 acc[2] = {};

  float4 v0 = *(const float4*)(xg);
  float4 v1 = *(const float4*)(xg + 4);
  for (int kt = 0; kt < K_TOT; kt += 64) {
    __syncthreads();   // previous iter's LDS reads done
    async_ld16(ag + kt, la0);
    async_ld16(ag + kt + 32, la1);
    ushort8 u;
    u[0] = f32_to_bf16(v0.x); u[1] = f32_to_bf16(v0.y);
    u[2] = f32_to_bf16(v0.z); u[3] = f32_to_bf16(v0.w);
    u[4] = f32_to_bf16(v1.x); u[5] = f32_to_bf16(v1.y);
    u[6] = f32_to_bf16(v1.z); u[7] = f32_to_bf16(v1.w);
    *(ushort8*)lx = u;
    *(ushort8*)(xbg + kt) = u;
    if (kt + 64 < K_TOT) {   // prefetch next x slice (latency hidden by MFMA)
      v0 = *(const float4*)(xg + kt + 64);
      v1 = *(const float4*)(xg + kt + 68);
    }
    __syncthreads();   // staged tile + ds_writes visible
#pragma unroll
    for (int ks = 0; ks < 2; ++ks) {
      bf16x8 xf = *(const bf16x8*)(px + ks * 1024);
#pragma unroll
      for (int j = 0; j < 2; ++j) {
        bf16x8 af = *(const bf16x8*)(pav + ks * 2048 + j * 16 * 32);
        acc[j] = __builtin_amdgcn_mfma_f32_16x16x32_bf16(xf, af, acc[j], 0, 0, 0);
      }
    }
  }
  const int row0 = m0 + wm * 16 + ((lane >> 4) << 2);
  const int col0 = wn * 32 + (lane & 15);
#pragma unroll
  for (int j = 0; j < 2; ++j)
#pragma unroll
    for (int r = 0; r < 4; ++r)
      Yb[(size_t)(row0 + r) * RANK + (col0 + j * 16)] = f32_to_bf16(acc[j][r]);
}

// ---------------- kernel 3: main GEMM, out = [Xb|Yb] @ [Weff|Bb]^T ----------
// m97 structure, BK=64, 64 K-iters + ONE peeled LoRA iteration.
// R4: Triton-style group swizzle (GROUP_M=32, M fastest) for L2/L3 locality.
__global__ __launch_bounds__(256) void gemm_kernel(
    const unsigned short* __restrict__ Xb,   // [M_TOT][K_TOT]
    const unsigned short* __restrict__ Wb,   // [N_TOT][K_TOT]
    const unsigned short* __restrict__ Yb,   // [M_TOT][RANK]
    const unsigned short* __restrict__ Bb,   // [N_TOT][RANK] (0.25 folded)
    float* __restrict__ out) {               // [M_TOT][N_TOT]
  __shared__ __align__(16) unsigned short As[2 * 128 * 32];  // 16 KB
  __shared__ __align__(16) unsigned short Bs[2 * 128 * 32];  // 16 KB

  const int tid = threadIdx.x;
  const int lane = tid & 63;
  const int wave = tid >> 6;
  const int wm = wave >> 1;
  const int wn = wave & 1;

  // group swizzle: 64 m-tiles x 32 n-tiles, groups of 32x32 blocks, m fastest
  const int pid = blockIdx.x;
  const int pid_m = ((pid >> 10) << 5) + (pid & 31);
  const int pid_n = (pid & 1023) >> 5;
  const int bM = pid_m * 128;
  const int bN = pid_n * 128;

  const int sRow = tid >> 2;        // 0..63
  const int sCol = (tid & 3) * 8;   // 0,8,16,24
  const unsigned short* xg0 = Xb + (size_t)(bM + sRow) * K_TOT + sCol;
  const unsigned short* xg1 = xg0 + (size_t)64 * K_TOT;
  const unsigned short* wg0 = Wb + (size_t)(bN + sRow) * K_TOT + sCol;
  const unsigned short* wg1 = wg0 + (size_t)64 * K_TOT;
  unsigned short* la00 = As + tid * 8;
  unsigned short* la01 = As + 64 * 32 + tid * 8;
  unsigned short* la10 = As + 128 * 32 + tid * 8;
  unsigned short* la11 = As + 128 * 32 + 64 * 32 + tid * 8;
  unsigned short* lb00 = Bs + tid * 8;
  unsigned short* lb01 = Bs + 64 * 32 + tid * 8;
  unsigned short* lb10 = Bs + 128 * 32 + tid * 8;
  unsigned short* lb11 = Bs + 128 * 32 + 64 * 32 + tid * 8;

  const unsigned short* pa = As + ((wm * 64) + (lane & 15)) * 32 + (lane >> 4) * 8;
  const unsigned short* pb = Bs + ((wn * 64) + (lane & 15)) * 32 + (lane >> 4) * 8;

  floatx4 acc[4][4] = {};

  for (int kt = 0; kt < K_TOT; kt += 64) {
    __syncthreads();
    async_ld16(xg0 + kt, la00);
    async_ld16(xg1 + kt, la01);
    async_ld16(xg0 + kt + 32, la10);
    async_ld16(xg1 + kt + 32, la11);
    async_ld16(wg0 + kt, lb00);
    async_ld16(wg1 + kt, lb01);
    async_ld16(wg0 + kt + 32, lb10);
    async_ld16(wg1 + kt + 32, lb11);
    __syncthreads();

#pragma unroll
    for (int ks = 0; ks < 2; ++ks) {
      const unsigned short* pak = pa + ks * 128 * 32;
      const unsigned short* pbk = pb + ks * 128 * 32;
      bf16x8 af[4], bf[4];
#pragma unroll
      for (int i = 0; i < 4; ++i) af[i] = *(const bf16x8*)(pak + i * 16 * 32);
#pragma unroll
      for (int j = 0; j < 4; ++j) bf[j] = *(const bf16x8*)(pbk + j * 16 * 32);
#pragma unroll
      for (int i = 0; i < 4; ++i)
#pragma unroll
        for (int j = 0; j < 4; ++j)
          acc[i][j] = __builtin_amdgcn_mfma_f32_16x16x32_bf16(af[i], bf[j], acc[i][j], 0, 0, 0);
    }
  }

  // peeled LoRA iteration: A-side = Yb [M][64], B-side = Bb [N][64]
  {
    const unsigned short* yg0 = Yb + (size_t)(bM + sRow) * RANK + sCol;
    const unsigned short* yg1 = yg0 + (size_t)64 * RANK;
    const unsigned short* bg0 = Bb + (size_t)(bN + sRow) * RANK + sCol;
    const unsigned short* bg1 = bg0 + (size_t)64 * RANK;
    __syncthreads();
    async_ld16(yg0, la00);
    async_ld16(yg1, la01);
    async_ld16(yg0 + 32, la10);
    async_ld16(yg1 + 32, la11);
    async_ld16(bg0, lb00);
    async_ld16(bg1, lb01);
    async_ld16(bg0 + 32, lb10);
    async_ld16(bg1 + 32, lb11);
    __syncthreads();
#pragma unroll
    for (int ks = 0; ks < 2; ++ks) {
      const unsigned short* pak = pa + ks * 128 * 32;
      const unsigned short* pbk = pb + ks * 128 * 32;
      bf16x8 af[4], bf[4];
#pragma unroll
      for (int i = 0; i < 4; ++i) af[i] = *(const bf16x8*)(pak + i * 16 * 32);
#pragma unroll
      for (int j = 0; j < 4; ++j) bf[j] = *(const bf16x8*)(pbk + j * 16 * 32);
#pragma unroll
      for (int i = 0; i < 4; ++i)
#pragma unroll
        for (int j = 0; j < 4; ++j)
          acc[i][j] = __builtin_amdgcn_mfma_f32_16x16x32_bf16(af[i], bf[j], acc[i][j], 0, 0, 0);
    }
  }

  const int row0 = bM + wm * 64 + ((lane >> 4) << 2);
  const int col0 = bN + wn * 64 + (lane & 15);
#pragma unroll
  for (int i = 0; i < 4; ++i)
#pragma unroll
    for (int j = 0; j < 4; ++j)
#pragma unroll
      for (int r = 0; r < 4; ++r)
        out[(size_t)(row0 + i * 16 + r) * N_TOT + (col0 + j * 16)] = acc[i][j][r];
}

extern "C" void kernel_launch(void* const* d_in, const int* in_sizes, int n_in,
                              void* d_out, int out_size, void* d_ws, size_t ws_size,
                              hipStream_t stream) {
  const float* x      = (const float*)d_in[0];   // [4,2048,4096] fp32
  const int*   wq     = (const int*)d_in[1];     // [4096,4096] int
  const float* wscale = (const float*)d_in[2];   // [1] fp32
  const float* lora_A = (const float*)d_in[3];   // [64,4096] fp32
  const float* lora_B = (const float*)d_in[4];   // [4096,64] fp32
  float* out = (float*)d_out;

  // workspace layout (bytes):
  // xb   @ 0          : 8192*4096*2 = 67108864
  // weff @ 67108864   : 4096*4096*2 = 33554432
  // yb   @ 100663296  : 8192*64*2   = 1048576
  // ab   @ 101711872  : 64*4096*2   = 524288
  // bb   @ 102236160  : 4096*64*2   = 524288
  char* ws = (char*)d_ws;
  unsigned short* xb   = (unsigned short*)(ws);
  unsigned short* weff = (unsigned short*)(ws + 67108864);
  unsigned short* yb   = (unsigned short*)(ws + 100663296);
  unsigned short* ab   = (unsigned short*)(ws + 101711872);
  unsigned short* bb   = (unsigned short*)(ws + 102236160);

  prep_kernel<<<16896, 256, 0, stream>>>(wq, wscale, lora_A, lora_B, weff, ab, bb);
  cvt_lora_kernel<<<256, 256, 0, stream>>>(x, ab, xb, yb);
  gemm_kernel<<<2048, 256, 0, stream>>>(xb, weff, yb, bb, out);
}